// Round 4
// baseline (476.260 us; speedup 1.0000x reference)
//
#include <hip/hip_runtime.h>
#include <stddef.h>

// Problem constants (match reference setup_inputs)
constexpr int N_NODES = 200000;
constexpr int N_EDGES = 200000;
constexpr int N_GRAPHS = 128;
constexpr int IN_F = 256;
constexpr int HID_F = 128;
constexpr int OUT_F = 128;
constexpr int OUT_W = OUT_F + HID_F; // 256 output cols per graph
constexpr int SCAN_NB = (N_NODES + 1023) / 1024; // 196 blocks
constexpr int EDGE_NB = (N_EDGES + 255) / 256;   // 782 blocks
constexpr int CHUNKS = 128;                      // mean k-split

typedef __attribute__((ext_vector_type(8))) short short8;   // bf16x8 MFMA A/B frag
typedef __attribute__((ext_vector_type(4))) float float4v;  // fp32x4 MFMA C/D frag

__device__ __forceinline__ short f2bf(float f) {
    union { float f; unsigned u; } v; v.f = f;
    unsigned r = v.u + 0x7fffu + ((v.u >> 16) & 1u);  // RNE
    return (short)(r >> 16);
}
__device__ __forceinline__ float bf2f(unsigned short s) {
    union { unsigned u; float f; } v; v.u = ((unsigned)s) << 16;
    return v.f;
}

// ---------------- consolidated init (r4) ----------------
// One launch replaces: memset(cursor), bounds_kernel, transpose_w_kernel,
// memset(rootlin). 782 blocks x 256 thr; block 0 additionally does the
// 129 binary searches for graph segment bounds.
__global__ __launch_bounds__(256) void init_kernel(
    const int* __restrict__ batch, const float* __restrict__ W1,
    const float* __restrict__ W2,
    int* __restrict__ cursor, float* __restrict__ rootlin,
    int* __restrict__ startv, int* __restrict__ cntg,
    short* __restrict__ Bt1, short* __restrict__ Bt2)
{
    __shared__ int s_start[N_GRAPHS + 1];
    const int t = threadIdx.x;
    const int gid = blockIdx.x * 256 + t;

    if (gid < N_NODES) cursor[gid] = 0;
    if (gid < N_GRAPHS * OUT_F) rootlin[gid] = 0.f;
    if (gid < 128 * IN_F) { // Bt1[n*256+k] = bf16(W1[k*128+n])
        int n = gid >> 8, k = gid & 255;
        Bt1[(size_t)n * IN_F + k] = f2bf(W1[(size_t)k * 128 + n]);
    } else if (gid < 128 * IN_F + 128 * HID_F) {
        int tw = gid - 128 * IN_F;
        int n = tw >> 7, k = tw & 127;
        Bt2[(size_t)n * HID_F + k] = f2bf(W2[(size_t)k * 128 + n]);
    }
    if (blockIdx.x == 0) {
        if (t <= N_GRAPHS) { // lower_bound(batch, g); g==128 -> N_NODES
            int g = t, lo = 0, hi = N_NODES;
            while (lo < hi) {
                int mid = (lo + hi) >> 1;
                if (batch[mid] < g) lo = mid + 1; else hi = mid;
            }
            s_start[t] = lo;
        }
        __syncthreads();
        if (t < N_GRAPHS) {
            startv[t] = s_start[t];
            cntg[t] = s_start[t + 1] - s_start[t];
        }
    }
}

__global__ void edge_prep_kernel(const int* __restrict__ dst, int* __restrict__ cntin, int E) {
    int e = blockIdx.x * blockDim.x + threadIdx.x;
    if (e < E) atomicAdd(&cntin[dst[e]], 1);
}

__global__ __launch_bounds__(1024) void scan_reduce_kernel(const int* __restrict__ cnt,
                                                           int* __restrict__ partial, int n) {
    __shared__ int sm[1024];
    int t = threadIdx.x;
    int i = blockIdx.x * 1024 + t;
    sm[t] = (i < n) ? cnt[i] : 0;
    __syncthreads();
    for (int ofs = 512; ofs > 0; ofs >>= 1) {
        if (t < ofs) sm[t] += sm[t + ofs];
        __syncthreads();
    }
    if (t == 0) partial[blockIdx.x] = sm[0];
}

__global__ void scan_base_kernel(int* __restrict__ partial, int nb) {
    __shared__ int sm[256];
    int t = threadIdx.x;
    sm[t] = (t < nb) ? partial[t] : 0;
    __syncthreads();
    for (int ofs = 1; ofs < 256; ofs <<= 1) {
        int v = (t >= ofs) ? sm[t - ofs] : 0;
        __syncthreads();
        sm[t] += v;
        __syncthreads();
    }
    if (t < nb) partial[t] = (t == 0) ? 0 : sm[t - 1];
}

// local scan + base -> rp[i], cur[i]; fused dinv[i] = rsqrt(1+indeg).
// cnt aliases cur: each thread reads cnt[i] before writing cur[i] (same index).
__global__ __launch_bounds__(1024) void scan_final_kernel(const int* __restrict__ cnt,
                                                          const int* __restrict__ partial,
                                                          int* __restrict__ rp,
                                                          int* __restrict__ cur,
                                                          float* __restrict__ dinv, int n) {
    __shared__ int sm[1024];
    int t = threadIdx.x;
    int i = blockIdx.x * 1024 + t;
    int v = (i < n) ? cnt[i] : 0;
    sm[t] = v;
    __syncthreads();
    for (int ofs = 1; ofs < 1024; ofs <<= 1) {
        int u = (t >= ofs) ? sm[t - ofs] : 0;
        __syncthreads();
        sm[t] += u;
        __syncthreads();
    }
    int base = partial[blockIdx.x];
    if (i < n) {
        int ex = base + sm[t] - v; // exclusive
        rp[i] = ex;
        cur[i] = ex;
        dinv[i] = rsqrtf(1.0f + (float)v);
        if (i == n - 1) rp[n] = ex + v;
    }
}

// Fused bucket + rootlin (r4): blocks [0,782) bucket edges; blocks [782,1038)
// compute rootlin with 8-way (g: 2 block-halves x 2 thread-quarters... net 4
// partial sums per (g,f)) k-split accumulated via atomicAdd into zeroed rootlin.
__global__ __launch_bounds__(256) void bucket_rootlin_kernel(
    const int* __restrict__ src, const int* __restrict__ dst,
    int* __restrict__ cur, int* __restrict__ adj,
    const float* __restrict__ x, const int* __restrict__ root_index,
    const float* __restrict__ W2, float* __restrict__ rootlin)
{
    int b = blockIdx.x;
    int t = threadIdx.x;
    if (b < EDGE_NB) {
        int e = b * 256 + t;
        if (e < N_EDGES) {
            int pos = atomicAdd(&cur[dst[e]], 1);
            adj[pos] = src[e];
        }
    } else {
        int rb = b - EDGE_NB;          // 0..255
        int g = rb >> 1;
        int f = t & 127;
        int k0 = (rb & 1) * 128 + (t >> 7) * 64;
        int r = root_index[g];
        const float* xr = x + (size_t)r * IN_F;
        float acc = 0.f;
        for (int k = k0; k < k0 + 64; ++k)
            acc += fmaxf(xr[k], 0.f) * W2[(size_t)(HID_F + k) * OUT_F + f];
        atomicAdd(&rootlin[(size_t)g * OUT_F + f], acc);
    }
}

// ---------------- conv2 aggregation, standalone ----------------
// hsag[d,k] = bf16( relu( dinv[d]*(hs1[d,k] + sum_in hs1[adj,k]) + b1[k] ) )
// No LDS, 8 threads/row, 1.6M threads -> TLP hides the random-row gather latency.
__global__ __launch_bounds__(256) void agg2_kernel(
    const unsigned short* __restrict__ hs1, const float* __restrict__ dinv,
    const float* __restrict__ b1v, const int* __restrict__ rp,
    const int* __restrict__ adj, unsigned short* __restrict__ hsag)
{
    int gid = blockIdx.x * 256 + threadIdx.x; // N_NODES*8 threads exactly
    int r = gid >> 3;
    int c0 = (gid & 7) * 16; // 16 shorts = 32B per thread
    const unsigned short* hp = hs1 + (size_t)r * 128 + c0;
    float sum[16];
    {
        short8 h0 = *(const short8*)hp;
        short8 h1 = *(const short8*)(hp + 8);
        #pragma unroll
        for (int q = 0; q < 8; ++q) {
            sum[q] = bf2f((unsigned short)h0[q]);
            sum[8 + q] = bf2f((unsigned short)h1[q]);
        }
    }
    int e0 = rp[r], e1 = rp[r + 1];
    for (int e = e0; e < e1; ++e) {
        const unsigned short* qp = hs1 + (size_t)adj[e] * 128 + c0;
        short8 h0 = *(const short8*)qp;
        short8 h1 = *(const short8*)(qp + 8);
        #pragma unroll
        for (int q = 0; q < 8; ++q) {
            sum[q] += bf2f((unsigned short)h0[q]);
            sum[8 + q] += bf2f((unsigned short)h1[q]);
        }
    }
    float di = dinv[r];
    short8 s0, s1;
    #pragma unroll
    for (int q = 0; q < 8; ++q) {
        s0[q] = f2bf(fmaxf(di * sum[q] + b1v[c0 + q], 0.f));
        s1[q] = f2bf(fmaxf(di * sum[8 + q] + b1v[c0 + 8 + q], 0.f));
    }
    unsigned short* op = hsag + (size_t)r * 128 + c0;
    *(short8*)op = s0;
    *(short8*)(op + 8) = s1;
}

// ---------------- bf16 MFMA GEMM ----------------
// out[M,128] = op(A)[M,KTOT] @ B[KTOT,128], epilogue v = dinv[row]*(acc [+ rootlin]),
// stored bf16. ABF16: A already bf16 row-major [M][KTOT] -> direct short8 staging.
template<int KTOT, bool ABF16, bool ADDROOT>
__global__ __launch_bounds__(256) void mfma_gemm_kernel(
    const void* __restrict__ Ap, const short* __restrict__ Bt,
    unsigned short* __restrict__ outp,
    const float* __restrict__ dinv,
    const float* __restrict__ rootlin, const int* __restrict__ batch)
{
    // stride 136 shorts = 272B: bank stride 68 == 4 mod 32 -> 2-way conflicts only (free, m136)
    __shared__ __align__(16) short As[64][136];
    __shared__ __align__(16) short Bs[128][136];

    const int tid = threadIdx.x;
    const int wave = tid >> 6;
    const int lane = tid & 63;
    const int quad = lane >> 4;
    const int l16  = lane & 15;
    const int row0 = blockIdx.x * 64;

    float4v acc[8];
    #pragma unroll
    for (int c = 0; c < 8; ++c) acc[c] = (float4v){0.f, 0.f, 0.f, 0.f};

    const int arow = tid >> 2;
    const int ac8 = (tid & 3) * 8;
    const int bn = tid >> 1;
    const int bk = (tid & 1) * 64;

    for (int kb = 0; kb < KTOT / 128; ++kb) {
        {
            const short* bp = Bt + (size_t)bn * KTOT + kb * 128 + bk;
            #pragma unroll
            for (int j = 0; j < 8; ++j)
                *(short8*)&Bs[bn][bk + 8 * j] = *(const short8*)(bp + 8 * j);
        }
        if (ABF16) {
            const unsigned short* A = (const unsigned short*)Ap;
            const unsigned short* ap = A + (size_t)(row0 + arow) * KTOT + kb * 128 + ac8;
            #pragma unroll
            for (int jj = 0; jj < 4; ++jj)
                *(short8*)&As[arow][ac8 + 32 * jj] = *(const short8*)(ap + 32 * jj);
        } else {
            const float* A = (const float*)Ap;
            const float* ap = A + (size_t)(row0 + arow) * KTOT + kb * 128 + ac8;
            #pragma unroll
            for (int jj = 0; jj < 4; ++jj) {
                float4 f0 = *(const float4*)(ap + 32 * jj);
                float4 f1 = *(const float4*)(ap + 32 * jj + 4);
                short8 s;
                s[0] = f2bf(f0.x); s[1] = f2bf(f0.y); s[2] = f2bf(f0.z); s[3] = f2bf(f0.w);
                s[4] = f2bf(f1.x); s[5] = f2bf(f1.y); s[6] = f2bf(f1.z); s[7] = f2bf(f1.w);
                *(short8*)&As[arow][ac8 + 32 * jj] = s;
            }
        }
        __syncthreads();
        #pragma unroll
        for (int ks = 0; ks < 4; ++ks) {
            short8 af = *(const short8*)&As[wave * 16 + l16][ks * 32 + quad * 8];
            #pragma unroll
            for (int c = 0; c < 8; ++c) {
                short8 bf = *(const short8*)&Bs[c * 16 + l16][ks * 32 + quad * 8];
                acc[c] = __builtin_amdgcn_mfma_f32_16x16x32_bf16(af, bf, acc[c], 0, 0, 0);
            }
        }
        __syncthreads();
    }

    #pragma unroll
    for (int r = 0; r < 4; ++r) {
        int row = row0 + wave * 16 + quad * 4 + r;
        float di = dinv[row];
        const float* rl = nullptr;
        if (ADDROOT) rl = rootlin + (size_t)batch[row] * 128;
        #pragma unroll
        for (int c = 0; c < 8; ++c) {
            int col = c * 16 + l16;
            float v = acc[c][r];
            if (ADDROOT) v += rl[col];
            outp[(size_t)row * 128 + col] = (unsigned short)f2bf(v * di);
        }
    }
}

// pmean[c][g][f] = chunk-sum over nodes of relu(dinv[i]*(hs2[i]+sum_in hs2[adj]) + b2)
// (r4: plain coalesced stores replace 2.1M contended device atomics)
// out[g,128:256] = n>0 ? dinv[r]*(hs1[r]+sum_in hs1[adj]) + b1 : 0   (c==0 blocks)
__global__ void mean_kernel(const unsigned short* __restrict__ hs2,
                            const unsigned short* __restrict__ hs1,
                            const float* __restrict__ dinv, const float* __restrict__ b1v,
                            const float* __restrict__ b2v, const int* __restrict__ root_index,
                            const int* __restrict__ cnt, const int* __restrict__ start,
                            const int* __restrict__ rp, const int* __restrict__ adj,
                            float* __restrict__ pmean, float* __restrict__ out)
{
    int g = blockIdx.x;
    int c = blockIdx.y;
    int f = threadIdx.x; // 128
    int s = start[g], n = cnt[g];
    int per = (n + CHUNKS - 1) / CHUNKS;
    int lo = s + c * per;
    int hi = min(s + n, lo + per);
    float bb = b2v[f];
    float accv = 0.f;
    for (int i = lo; i < hi; ++i) {
        float v = bf2f(hs2[(size_t)i * 128 + f]);
        int e0 = rp[i], e1 = rp[i + 1];
        for (int e = e0; e < e1; ++e)
            v += bf2f(hs2[(size_t)adj[e] * 128 + f]);
        accv += fmaxf(dinv[i] * v + bb, 0.f);
    }
    pmean[(size_t)c * (N_GRAPHS * 128) + g * 128 + f] = accv; // always stored
    if (c == 0) {
        int r = root_index[g];
        float v = 0.f;
        if (n > 0) {
            v = bf2f(hs1[(size_t)r * 128 + f]);
            int e0 = rp[r], e1 = rp[r + 1];
            for (int e = e0; e < e1; ++e)
                v += bf2f(hs1[(size_t)adj[e] * 128 + f]);
            v = dinv[r] * v + b1v[f];
        }
        out[(size_t)g * OUT_W + HID_F + f] = v;
    }
}

// out[g,0:128] = (1/n) * sum_c pmean[c][g][f]
__global__ void meanreduce_kernel(const float* __restrict__ pmean,
                                  const int* __restrict__ cnt,
                                  float* __restrict__ out)
{
    int g = blockIdx.x;
    int f = threadIdx.x;
    float s = 0.f;
    for (int c = 0; c < CHUNKS; ++c)
        s += pmean[(size_t)c * (N_GRAPHS * 128) + g * 128 + f];
    out[(size_t)g * OUT_W + f] = s / (float)max(cnt[g], 1);
}

// ---------------- launch ----------------

static inline size_t align_up(size_t x, size_t a) { return (x + a - 1) / a * a; }

extern "C" void kernel_launch(void* const* d_in, const int* in_sizes, int n_in,
                              void* d_out, int out_size, void* d_ws, size_t ws_size,
                              hipStream_t stream) {
    const float* x = (const float*)d_in[0];
    const int* ei = (const int*)d_in[1];
    const int* batch = (const int*)d_in[2];
    const int* root = (const int*)d_in[3];
    const float* W1 = (const float*)d_in[4];
    const float* b1 = (const float*)d_in[5];
    const float* W2 = (const float*)d_in[6];
    const float* b2 = (const float*)d_in[7];
    float* out = (float*)d_out;

    const int* src = ei;
    const int* dst = ei + N_EDGES;

    // workspace carve-up
    char* ws = (char*)d_ws;
    size_t off = 0;
    const size_t NB16 = (size_t)N_NODES * 128 * sizeof(unsigned short); // 51.2 MB

    float* dinv = (float*)(ws + off);    off = align_up(off + (size_t)N_NODES * sizeof(float), 256);
    int* cntg = (int*)(ws + off);        off = align_up(off + N_GRAPHS * sizeof(int), 256);
    int* startv = (int*)(ws + off);      off = align_up(off + N_GRAPHS * sizeof(int), 256);
    float* rootlin = (float*)(ws + off); off = align_up(off + (size_t)N_GRAPHS * OUT_F * sizeof(float), 256);
    short* Bt1 = (short*)(ws + off);     off = align_up(off + (size_t)128 * IN_F * sizeof(short), 256);
    short* Bt2 = (short*)(ws + off);     off = align_up(off + (size_t)128 * HID_F * sizeof(short), 256);
    int* rowptr = (int*)(ws + off);      off = align_up(off + (size_t)(N_NODES + 1) * sizeof(int), 256);
    int* cursor = (int*)(ws + off);      off = align_up(off + (size_t)N_NODES * sizeof(int), 256);
    int* partial = (int*)(ws + off);     off = align_up(off + (size_t)SCAN_NB * sizeof(int), 256);
    int* adj = (int*)(ws + off);         off = align_up(off + (size_t)N_EDGES * sizeof(int), 256);
    float* pmean = (float*)(ws + off);   off = align_up(off + (size_t)CHUNKS * N_GRAPHS * 128 * sizeof(float), 256);
    unsigned short* hs1 = (unsigned short*)(ws + off);  off = align_up(off + NB16, 256);
    unsigned short* hs2 = (unsigned short*)(ws + off);  off = align_up(off + NB16, 256);
    unsigned short* hsag = (unsigned short*)(ws + off); off = align_up(off + NB16, 256);
    (void)ws_size; (void)n_in; (void)in_sizes; (void)out_size;

    // consolidated init: cursor-zero, rootlin-zero, bounds, weight transposes
    init_kernel<<<EDGE_NB, 256, 0, stream>>>(batch, W1, W2, cursor, rootlin,
                                             startv, cntg, Bt1, Bt2);
    // in-degree -> CSR-by-dst via hierarchical scan (+ fused dinv)
    edge_prep_kernel<<<EDGE_NB, 256, 0, stream>>>(dst, cursor, N_EDGES);
    scan_reduce_kernel<<<SCAN_NB, 1024, 0, stream>>>(cursor, partial, N_NODES);
    scan_base_kernel<<<1, 256, 0, stream>>>(partial, SCAN_NB);
    scan_final_kernel<<<SCAN_NB, 1024, 0, stream>>>(cursor, partial, rowptr, cursor, dinv, N_NODES);
    // bucket edges + rootlin in one launch
    bucket_rootlin_kernel<<<EDGE_NB + 2 * N_GRAPHS, 256, 0, stream>>>(
        src, dst, cursor, adj, x, root, W2, rootlin);

    // conv1 linear: hs1 = bf16( dinv .* (x @ W1) )
    mfma_gemm_kernel<IN_F, false, false><<<N_NODES / 64, 256, 0, stream>>>(
        x, Bt1, hs1, dinv, nullptr, nullptr);

    // conv2 aggregation (standalone, TLP-rich): hsag = relu(dinv.*(hs1+gather)+b1)
    agg2_kernel<<<(N_NODES * 8) / 256, 256, 0, stream>>>(hs1, dinv, b1, rowptr, adj, hsag);

    // conv2 linear (pure streaming bf16 GEMM):
    // hs2 = bf16( dinv .* ( hsag @ W2[0:128] + rootlin[batch] ) )
    mfma_gemm_kernel<HID_F, true, true><<<N_NODES / 64, 256, 0, stream>>>(
        hsag, Bt2, hs2, dinv, rootlin, batch);

    // conv2-aggregation + relu + graph mean partials + root gather (atomic-free)
    dim3 mg(N_GRAPHS, CHUNKS);
    mean_kernel<<<mg, 128, 0, stream>>>(hs2, hs1, dinv, b1, b2, root, cntg, startv,
                                        rowptr, adj, pmean, out);
    meanreduce_kernel<<<N_GRAPHS, 128, 0, stream>>>(pmean, cntg, out);
}